// Round 3
// baseline (3226.324 us; speedup 1.0000x reference)
//
#include <hip/hip_runtime.h>
#include <hip/hip_bf16.h>

// MXLlamaMLP: out = mxlin(silu(mxlin(x,w_gate)) * mxlin(x,w_up), w_down)
// All qdq outputs have <=4 significant bits * pow2 scale -> exact in bf16,
// so the fp32-reference einsums are computed with bf16 MFMA (fp32 accum).
//
// Pipeline:
//   1. mx_quant_all: x, w_gate, w_up, w_down -> bf16 (group-32 MX E4M3 qdq), 1 launch
//   2. gemm_gateup: G=Xq*Wg^T, U=Xq*Wu^T fused; epilogue silu(g)*u + in-register
//      group-32 qdq along FFN -> Tq bf16  (avoids 344MB fp32 intermediate)
//   3. gemm_down: Out = Tq*Wd^T -> fp32
// R1: + bijective XCD swizzle on both GEMM grids (T1; grids % 8 == 0).
// R2: merged 4 quant launches into 1 (saves ~3 launch overheads; no other change —
//     still no GPU, holding the verified-structure baseline until counters exist).

typedef __attribute__((ext_vector_type(8))) short short8;
typedef __attribute__((ext_vector_type(4))) float f32x4;

#define HID 4096
#define FFN 11008
#define MROWS 8192  // B*S = 4*2048

// ---------------- MX qdq helpers ----------------
// shared_exp = floor(log2(amax)) - 7 ; scale = 2^shared_exp
__device__ __forceinline__ void mx_scales(float am, float& scale, float& inv) {
  int e = (int)((__float_as_uint(am) >> 23) & 255) - 127;  // floor(log2) for normals
  if (e < -110) e = -110;  // guard amax==0/denormal (never hit with this data)
  scale = __uint_as_float((unsigned)(e + 120) << 23);  // 2^(e-7)
  inv   = __uint_as_float((unsigned)(134 - e) << 23);  // 2^(7-e)
}

// per-element: p = clip(floor(log2|xs|), -6, 7); q = RNE(xs/2^(p-3))*2^(p-3); clip 240
__device__ __forceinline__ float mx_qdq1(float x, float inv, float scale) {
  float xs = __fmul_rn(x, inv);                     // exact (pow2)
  int p = (int)((__float_as_uint(xs) >> 23) & 255) - 127;
  p = p < -6 ? -6 : (p > 7 ? 7 : p);
  float si = __uint_as_float((unsigned)(130 - p) << 23);  // 2^(3-p)
  float st = __uint_as_float((unsigned)(124 + p) << 23);  // 2^(p-3)
  float q = rintf(__fmul_rn(xs, si)) * st;          // rintf = RNE, matches jnp.round
  q = fminf(fmaxf(q, -240.0f), 240.0f);
  return __fmul_rn(q, scale);                       // <=4 sig bits -> exact in bf16
}

__device__ __forceinline__ unsigned short f2bf(float f) {
  unsigned u = __float_as_uint(f);
  return (unsigned short)((u + 0x7fffu + ((u >> 16) & 1u)) >> 16);
}

// ---------------- group-32 quantize, all 4 tensors in one launch ----------------
// 8 lanes per group, float4 per lane; amax via 3x shfl_xor within the 8-lane cluster.
// Region branches are wave-uniform except at the 3 tensor boundaries.
__global__ void mx_quant_all(const float* __restrict__ x,  const float* __restrict__ wg,
                             const float* __restrict__ wu, const float* __restrict__ wd,
                             __hip_bfloat16* __restrict__ xq, __hip_bfloat16* __restrict__ wgq,
                             __hip_bfloat16* __restrict__ wuq, __hip_bfloat16* __restrict__ wdq) {
  const long NGX = (long)MROWS * HID / 32;  // 1,048,576
  const long NGW = (long)FFN * HID / 32;    // 1,409,024
  const long TOTAL = NGX + 3 * NGW;
  long tid = (long)blockIdx.x * blockDim.x + threadIdx.x;
  long nthr = (long)gridDim.x * blockDim.x;
  int l8 = threadIdx.x & 7;
  for (long g = tid >> 3; g < TOTAL; g += (nthr >> 3)) {
    const float* in;
    __hip_bfloat16* out;
    long off;
    if (g < NGX)               { in = x;  out = xq;  off = g; }
    else if (g < NGX + NGW)    { in = wg; out = wgq; off = g - NGX; }
    else if (g < NGX + 2*NGW)  { in = wu; out = wuq; off = g - NGX - NGW; }
    else                       { in = wd; out = wdq; off = g - NGX - 2*NGW; }
    float4 v = reinterpret_cast<const float4*>(in + (off << 5))[l8];
    float am = fmaxf(fmaxf(fabsf(v.x), fabsf(v.y)), fmaxf(fabsf(v.z), fabsf(v.w)));
    am = fmaxf(am, __shfl_xor(am, 1));
    am = fmaxf(am, __shfl_xor(am, 2));
    am = fmaxf(am, __shfl_xor(am, 4));
    float sc, inv;
    mx_scales(am, sc, inv);
    union { unsigned short h[4]; ushort4 u4; } o;
    o.h[0] = f2bf(mx_qdq1(v.x, inv, sc));
    o.h[1] = f2bf(mx_qdq1(v.y, inv, sc));
    o.h[2] = f2bf(mx_qdq1(v.z, inv, sc));
    o.h[3] = f2bf(mx_qdq1(v.w, inv, sc));
    reinterpret_cast<ushort4*>(out + (off << 5))[l8] = o.u4;
  }
}

// ---------------- staging helper: 1KiB per wave-issue, linear LDS dest ----------------
#define GLOAD_LDS16(gsrc, ldst)                                                        \
  __builtin_amdgcn_global_load_lds((const __attribute__((address_space(1))) void*)(gsrc), \
                                   (__attribute__((address_space(3))) void*)(ldst), 16, 0, 0)

// bijective XCD swizzle (grid % 8 == 0): consecutive blocks -> same XCD chunk
__device__ __forceinline__ int xcd_swz(int bid, int nwg) {
  int cpx = nwg >> 3;  // nwg % 8 == 0 guaranteed by caller
  return (bid & 7) * cpx + (bid >> 3);
}

// ---------------- GEMM1: fused gate+up, epilogue silu*u + qdq -> Tq bf16 ----------------
// 128x128 tile, BK=64, 4 waves (2x2), 16x16x32 bf16 MFMA (m97 structure).
__global__ __launch_bounds__(256, 2) void gemm_gateup(
    const __hip_bfloat16* __restrict__ Xq,   // [MROWS, HID]
    const __hip_bfloat16* __restrict__ Wg,   // [FFN, HID]
    const __hip_bfloat16* __restrict__ Wu,   // [FFN, HID]
    __hip_bfloat16* __restrict__ Tq) {       // [MROWS, FFN]
  __shared__ __hip_bfloat16 As[128][64];
  __shared__ __hip_bfloat16 Bg[128][64];
  __shared__ __hip_bfloat16 Bu[128][64];

  const int tid = threadIdx.x;
  const int lane = tid & 63;
  const int wid = tid >> 6;
  const int wr = wid >> 1, wc = wid & 1;  // 2x2 wave grid, 64x64 per wave
  const int NBX = FFN / 128;              // 86
  const int bid = xcd_swz(blockIdx.x, NBX * (MROWS / 128));
  const int brow = (bid / NBX) * 128;
  const int bcol = (bid % NBX) * 128;

  f32x4 accG[4][4], accU[4][4];
#pragma unroll
  for (int i = 0; i < 4; i++)
#pragma unroll
    for (int j = 0; j < 4; j++) {
      accG[i][j] = (f32x4){0.f, 0.f, 0.f, 0.f};
      accU[i][j] = (f32x4){0.f, 0.f, 0.f, 0.f};
    }

  const int srow = lane >> 3;        // row-in-chunk (8 rows of 128B per 1KiB issue)
  const int scol = (lane & 7) * 8;   // k-elem offset within row
  const int lr = lane & 15;          // fragment row (A) / row-of-W (B)
  const int kq = lane >> 4;          // k-quarter

  for (int kt = 0; kt < HID / 64; ++kt) {
    const int k0 = kt * 64;
#pragma unroll
    for (int i = 0; i < 4; ++i) {
      int ci = wid * 4 + i;          // chunk id 0..15, wave-uniform
      int row = ci * 8 + srow;
      GLOAD_LDS16(Xq + (size_t)(brow + row) * HID + k0 + scol, (char*)&As[0][0] + ci * 1024);
      GLOAD_LDS16(Wg + (size_t)(bcol + row) * HID + k0 + scol, (char*)&Bg[0][0] + ci * 1024);
      GLOAD_LDS16(Wu + (size_t)(bcol + row) * HID + k0 + scol, (char*)&Bu[0][0] + ci * 1024);
    }
    __syncthreads();
#pragma unroll
    for (int kc = 0; kc < 2; ++kc) {
      const int ko = kc * 32 + kq * 8;
      short8 a[4], bg[4], bu[4];
#pragma unroll
      for (int f = 0; f < 4; ++f) {
        a[f]  = *(const short8*)&As[wr * 64 + f * 16 + lr][ko];
        bg[f] = *(const short8*)&Bg[wc * 64 + f * 16 + lr][ko];
        bu[f] = *(const short8*)&Bu[wc * 64 + f * 16 + lr][ko];
      }
#pragma unroll
      for (int m = 0; m < 4; m++)
#pragma unroll
        for (int n = 0; n < 4; n++) {
          accG[m][n] = __builtin_amdgcn_mfma_f32_16x16x32_bf16(a[m], bg[n], accG[m][n], 0, 0, 0);
          accU[m][n] = __builtin_amdgcn_mfma_f32_16x16x32_bf16(a[m], bu[n], accU[m][n], 0, 0, 0);
        }
    }
    __syncthreads();
  }

  // Epilogue: t=silu(g)*u; group-32 qdq along FFN. C-frag: col=lane&15, row=(lane>>4)*4+reg.
  // Group of 32 cols = 2 adjacent 16-wide n-frags; amax across the 16-lane quarter-group
  // (shfl_xor 1,2,4,8 keeps bits 4-5 = q fixed -> reduces over the 16 lanes holding one row).
  const int q = lane >> 4;
  const int c = lane & 15;
#pragma unroll
  for (int m = 0; m < 4; m++) {
    int grow = brow + wr * 64 + m * 16 + q * 4;
#pragma unroll
    for (int j = 0; j < 4; j++) {
      size_t rowoff = (size_t)(grow + j) * FFN + bcol + wc * 64;
#pragma unroll
      for (int P = 0; P < 2; P++) {
        float g0 = accG[m][2 * P][j], g1 = accG[m][2 * P + 1][j];
        float u0 = accU[m][2 * P][j], u1 = accU[m][2 * P + 1][j];
        float t0 = u0 * (g0 / (1.0f + expf(-g0)));
        float t1 = u1 * (g1 / (1.0f + expf(-g1)));
        float am = fmaxf(fabsf(t0), fabsf(t1));
        am = fmaxf(am, __shfl_xor(am, 1));
        am = fmaxf(am, __shfl_xor(am, 2));
        am = fmaxf(am, __shfl_xor(am, 4));
        am = fmaxf(am, __shfl_xor(am, 8));  // stays within 16-lane group
        float sc, inv;
        mx_scales(am, sc, inv);
        reinterpret_cast<unsigned short*>(Tq)[rowoff + P * 32 + c]      = f2bf(mx_qdq1(t0, inv, sc));
        reinterpret_cast<unsigned short*>(Tq)[rowoff + P * 32 + 16 + c] = f2bf(mx_qdq1(t1, inv, sc));
      }
    }
  }
}

// ---------------- GEMM2: Out = Tq * Wd^T (fp32 out) ----------------
__global__ __launch_bounds__(256, 3) void gemm_down(
    const __hip_bfloat16* __restrict__ Tq,   // [MROWS, FFN]
    const __hip_bfloat16* __restrict__ Wd,   // [HID, FFN]
    float* __restrict__ Out) {               // [MROWS, HID]
  __shared__ __hip_bfloat16 As[128][64];
  __shared__ __hip_bfloat16 Bs[128][64];

  const int tid = threadIdx.x;
  const int lane = tid & 63;
  const int wid = tid >> 6;
  const int wr = wid >> 1, wc = wid & 1;
  const int NBX = HID / 128;               // 32
  const int bid = xcd_swz(blockIdx.x, NBX * (MROWS / 128));
  const int brow = (bid / NBX) * 128;
  const int bcol = (bid % NBX) * 128;

  f32x4 acc[4][4];
#pragma unroll
  for (int i = 0; i < 4; i++)
#pragma unroll
    for (int j = 0; j < 4; j++) acc[i][j] = (f32x4){0.f, 0.f, 0.f, 0.f};

  const int srow = lane >> 3;
  const int scol = (lane & 7) * 8;
  const int lr = lane & 15;
  const int kq = lane >> 4;

  for (int kt = 0; kt < FFN / 64; ++kt) {
    const int k0 = kt * 64;
#pragma unroll
    for (int i = 0; i < 4; ++i) {
      int ci = wid * 4 + i;
      int row = ci * 8 + srow;
      GLOAD_LDS16(Tq + (size_t)(brow + row) * FFN + k0 + scol, (char*)&As[0][0] + ci * 1024);
      GLOAD_LDS16(Wd + (size_t)(bcol + row) * FFN + k0 + scol, (char*)&Bs[0][0] + ci * 1024);
    }
    __syncthreads();
#pragma unroll
    for (int kc = 0; kc < 2; ++kc) {
      const int ko = kc * 32 + kq * 8;
      short8 a[4], b[4];
#pragma unroll
      for (int f = 0; f < 4; ++f) {
        a[f] = *(const short8*)&As[wr * 64 + f * 16 + lr][ko];
        b[f] = *(const short8*)&Bs[wc * 64 + f * 16 + lr][ko];
      }
#pragma unroll
      for (int m = 0; m < 4; m++)
#pragma unroll
        for (int n = 0; n < 4; n++)
          acc[m][n] = __builtin_amdgcn_mfma_f32_16x16x32_bf16(a[m], b[n], acc[m][n], 0, 0, 0);
    }
    __syncthreads();
  }

  const int q = lane >> 4;
  const int c = lane & 15;
#pragma unroll
  for (int m = 0; m < 4; m++) {
    int grow = brow + wr * 64 + m * 16 + q * 4;
#pragma unroll
    for (int j = 0; j < 4; j++) {
      size_t rowoff = (size_t)(grow + j) * HID + bcol + wc * 64;
#pragma unroll
      for (int n = 0; n < 4; n++) Out[rowoff + n * 16 + c] = acc[m][n][j];
    }
  }
}

// ---------------- launch ----------------
extern "C" void kernel_launch(void* const* d_in, const int* in_sizes, int n_in,
                              void* d_out, int out_size, void* d_ws, size_t ws_size,
                              hipStream_t stream) {
  const float* x  = (const float*)d_in[0];
  const float* wg = (const float*)d_in[1];
  const float* wu = (const float*)d_in[2];
  const float* wd = (const float*)d_in[3];
  float* out = (float*)d_out;

  char* ws = (char*)d_ws;
  const size_t SZ_X = (size_t)MROWS * HID * 2;   // 64 MiB
  const size_t SZ_W = (size_t)FFN * HID * 2;     // 86 MiB each
  __hip_bfloat16* Xq  = (__hip_bfloat16*)(ws);
  __hip_bfloat16* Wgq = (__hip_bfloat16*)(ws + SZ_X);
  __hip_bfloat16* Wuq = (__hip_bfloat16*)(ws + SZ_X + SZ_W);
  __hip_bfloat16* Wdq = (__hip_bfloat16*)(ws + SZ_X + 2 * SZ_W);
  __hip_bfloat16* Tq  = (__hip_bfloat16*)(ws + SZ_X + 3 * SZ_W);  // 172 MiB
  // total ws use: 64 + 3*86 + 172 = 494 MiB

  mx_quant_all<<<2048, 256, 0, stream>>>(x, wg, wu, wd, Xq, Wgq, Wuq, Wdq);

  dim3 g1(FFN / 128 * (MROWS / 128));  // 5504 blocks, 1D for swizzle
  gemm_gateup<<<g1, 256, 0, stream>>>(Xq, Wgq, Wuq, Tq);

  dim3 g2(HID / 128 * (MROWS / 128));  // 2048 blocks
  gemm_down<<<g2, 256, 0, stream>>>(Tq, Wdq, out);
}